// Round 4
// baseline (156.339 us; speedup 1.0000x reference)
//
#include <hip/hip_runtime.h>

typedef __attribute__((ext_vector_type(8))) short bf16x8;
typedef __attribute__((ext_vector_type(4))) float f32x4;

#define NPB 4   // 4 waves/block, 1 node per wave

__device__ __forceinline__ short f2bf(float f) {
  unsigned u = __float_as_uint(f);
  u += 0x7fffu + ((u >> 16) & 1u);   // RNE to bf16
  return (short)(u >> 16);
}

__device__ __forceinline__ bf16x8 ldsfrag(const int* p) {
  union { int4 i; bf16x8 b; } u;
  u.i = *reinterpret_cast<const int4*>(p);
  return u.b;
}

// One wave per node (32 edges = 2 x 16-row tiles).
// hT = A(W1^T tile) * B(s^T); D leaves each lane holding h of ONE edge ->
// ready A-frag of h under k-permutation pi(c,j) folded into W2 staging.
// Right-branch bias rides in the spare k=20 slot of the padded expansion.
__global__ __launch_bounds__(256) void deepdft_v4(
    const float* __restrict__ S,     // [N,K,1,32]
    const float* __restrict__ V,     // [N,K,3,32]
    const float* __restrict__ EXPN,  // [N,K,20]
    const float* __restrict__ DIR,   // [N,K,3]
    const float* __restrict__ MASK,  // [N,K,1]
    const float* __restrict__ DIST,  // [N,K,1]
    const float* __restrict__ W1,    // [32,32]
    const float* __restrict__ B1,    // [32]
    const float* __restrict__ W2,    // [32,96]
    const float* __restrict__ B2,    // [96]
    const float* __restrict__ WR,    // [20,96]
    const float* __restrict__ BR,    // [96]
    float* __restrict__ OUT,         // [N,1,32] ++ [N,3,32]
    int n_nodes)
{
  __shared__ int wlds[14][256];   // 14 fragment tiles x 64 lanes x 16B

  const int tid = threadIdx.x, wid = tid >> 6, l = tid & 63;
  const int col16 = l & 15, c = l >> 4, kc = c << 3;

  const int n = blockIdx.x * NPB + wid;
  const bool active = (n < n_nodes);
  const int eb0 = n << 5;

  // ---- pipeline registers ----
  float4 sS0, sS1, sE0, sE1;
  float sv[24], sd[4], smk[4], sdir[12];
  float acc[8];

  auto issueS = [&](int ebase) {
    const float* sp = S + ((size_t)(ebase + col16)) * 32 + kc;
    sS0 = *reinterpret_cast<const float4*>(sp);
    sS1 = *reinterpret_cast<const float4*>(sp + 4);
    const float* ep = EXPN + ((size_t)(ebase + col16)) * 20;
    if (c < 2) {
      sE0 = *reinterpret_cast<const float4*>(ep + kc);
      sE1 = *reinterpret_cast<const float4*>(ep + kc + 4);
    } else if (c == 2) {
      sE0 = *reinterpret_cast<const float4*>(ep + 16);
      sE1 = make_float4(1.f, 0.f, 0.f, 0.f);      // k=20 slot = 1 -> +br
    } else {
      sE0 = make_float4(0.f, 0.f, 0.f, 0.f);
      sE1 = make_float4(0.f, 0.f, 0.f, 0.f);
    }
  };

  auto issueV = [&](int ebase) {
    #pragma unroll
    for (int r = 0; r < 4; ++r) {
      int er = ebase + (c << 2) + r;
      sd[r]  = DIST[er];
      smk[r] = MASK[er];
      sdir[3*r+0] = DIR[3*er+0];
      sdir[3*r+1] = DIR[3*er+1];
      sdir[3*r+2] = DIR[3*er+2];
      const float* vp = V + (size_t)er * 96 + col16;
      #pragma unroll
      for (int t = 0; t < 2; ++t)
        #pragma unroll
        for (int ax = 0; ax < 3; ++ax)
          sv[(r*2 + t)*3 + ax] = vp[ax*32 + t*16];
    }
  };

  // cold-start loads issued BEFORE weight staging: latency hidden by staging
  if (active) { issueS(eb0); issueV(eb0); }

  // ---- stage weight fragments (bf16) into LDS, split across waves ----
  for (int t = wid; t < 14; t += 4) {
    int q[4];
    #pragma unroll
    for (int jj = 0; jj < 4; ++jj) {
      float f0, f1;
      if (t < 2) {                       // W1^T A-frag (== W1 B-frag data)
        int k0 = kc + 2*jj;
        int co = (t << 4) + col16;
        f0 = W1[k0*32 + co]; f1 = W1[(k0+1)*32 + co];
      } else if (t < 8) {                // W2 B-frag, k permuted by pi(c,j)
        int j0 = 2*jj;
        int feat = (j0 < 4) ? (4*c + j0) : (16 + 4*c + (j0 - 4));
        int co = ((t-2) << 4) + col16;
        f0 = W2[feat*96 + co]; f1 = W2[(feat+1)*96 + co];
      } else {                           // WR B-frag, row20 = BR (bias), rest 0
        int k0 = kc + 2*jj;
        int co = ((t-8) << 4) + col16;
        f0 = (k0   < 20) ? WR[k0*96 + co]     : ((k0   == 20) ? BR[co] : 0.f);
        f1 = (k0+1 < 20) ? WR[(k0+1)*96 + co] : ((k0+1 == 20) ? BR[co] : 0.f);
      }
      q[jj] = ((int)(unsigned short)f2bf(f0)) |
              (((int)(unsigned short)f2bf(f1)) << 16);
    }
    *reinterpret_cast<int4*>(&wlds[t][l << 2]) = make_int4(q[0], q[1], q[2], q[3]);
  }

  // b1 per-lane (feature = 16t + 4c + r), b2 per-lane scalars
  f32x4 b1a, b1b;
  {
    float4 t0 = *reinterpret_cast<const float4*>(B1 + 4*c);
    float4 t1 = *reinterpret_cast<const float4*>(B1 + 16 + 4*c);
    b1a[0]=t0.x; b1a[1]=t0.y; b1a[2]=t0.z; b1a[3]=t0.w;
    b1b[0]=t1.x; b1b[1]=t1.y; b1b[2]=t1.z; b1b[3]=t1.w;
  }
  float b2v[6];
  #pragma unroll
  for (int t = 0; t < 6; ++t) b2v[t] = B2[(t << 4) + col16];

  __syncthreads();

  if (!active) return;

  const bf16x8 w1a0 = ldsfrag(&wlds[0][l << 2]);
  const bf16x8 w1a1 = ldsfrag(&wlds[1][l << 2]);

  // computes the currently-staged edge-group; optionally prefetches ebNext
  auto body = [&](int ebNext, bool pf) {
    bf16x8 bs, ae;
    bs[0]=f2bf(sS0.x); bs[1]=f2bf(sS0.y); bs[2]=f2bf(sS0.z); bs[3]=f2bf(sS0.w);
    bs[4]=f2bf(sS1.x); bs[5]=f2bf(sS1.y); bs[6]=f2bf(sS1.z); bs[7]=f2bf(sS1.w);
    ae[0]=f2bf(sE0.x); ae[1]=f2bf(sE0.y); ae[2]=f2bf(sE0.z); ae[3]=f2bf(sE0.w);
    ae[4]=f2bf(sE1.x); ae[5]=f2bf(sE1.y); ae[6]=f2bf(sE1.z); ae[7]=f2bf(sE1.w);
    if (pf) issueS(ebNext);   // S/EXPN consumed -> re-issue immediately

    const f32x4 z = {0.f, 0.f, 0.f, 0.f};
    // right branch (independent of h chain; bias via k=20)
    f32x4 rA0 = __builtin_amdgcn_mfma_f32_16x16x32_bf16(ae, ldsfrag(&wlds[ 8][l<<2]), z, 0,0,0);
    f32x4 rA1 = __builtin_amdgcn_mfma_f32_16x16x32_bf16(ae, ldsfrag(&wlds[ 9][l<<2]), z, 0,0,0);
    f32x4 rB0 = __builtin_amdgcn_mfma_f32_16x16x32_bf16(ae, ldsfrag(&wlds[10][l<<2]), z, 0,0,0);
    f32x4 rB1 = __builtin_amdgcn_mfma_f32_16x16x32_bf16(ae, ldsfrag(&wlds[11][l<<2]), z, 0,0,0);
    f32x4 rC0 = __builtin_amdgcn_mfma_f32_16x16x32_bf16(ae, ldsfrag(&wlds[12][l<<2]), z, 0,0,0);
    f32x4 rC1 = __builtin_amdgcn_mfma_f32_16x16x32_bf16(ae, ldsfrag(&wlds[13][l<<2]), z, 0,0,0);

    // hT: D row = feature, col = edge -> lane-local h row per edge
    f32x4 h0 = __builtin_amdgcn_mfma_f32_16x16x32_bf16(w1a0, bs, b1a, 0,0,0);
    f32x4 h1 = __builtin_amdgcn_mfma_f32_16x16x32_bf16(w1a1, bs, b1b, 0,0,0);

    float wr_[4];
    #pragma unroll
    for (int r = 0; r < 4; ++r) {
      float wv = 0.f;
      if (sd[r] < 5.f)
        wv = smk[r] * 0.5f * (__cosf(0.62831853071795865f * sd[r]) + 1.f);
      wr_[r] = wv;
    }

    bf16x8 ah;   // A-frag of h under pi(c,j)
    #pragma unroll
    for (int j = 0; j < 4; ++j) {
      float x = h0[j]; x = __fdividef(x, 1.f + __expf(-x)); ah[j] = f2bf(x);
    }
    #pragma unroll
    for (int j = 0; j < 4; ++j) {
      float x = h1[j]; x = __fdividef(x, 1.f + __expf(-x)); ah[4+j] = f2bf(x);
    }

    #pragma unroll
    for (int tt = 0; tt < 2; ++tt) {
      f32x4 lA = __builtin_amdgcn_mfma_f32_16x16x32_bf16(ah, ldsfrag(&wlds[2+tt][l<<2]), z, 0,0,0);
      f32x4 lB = __builtin_amdgcn_mfma_f32_16x16x32_bf16(ah, ldsfrag(&wlds[4+tt][l<<2]), z, 0,0,0);
      f32x4 lC = __builtin_amdgcn_mfma_f32_16x16x32_bf16(ah, ldsfrag(&wlds[6+tt][l<<2]), z, 0,0,0);
      f32x4 rA = tt ? rA1 : rA0;
      f32x4 rB = tt ? rB1 : rB0;
      f32x4 rC = tt ? rC1 : rC0;
      #pragma unroll
      for (int r = 0; r < 4; ++r) {
        float la = lA[r] + b2v[tt];
        float lb = lB[r] + b2v[2+tt];
        float lc = lC[r] + b2v[4+tt];
        float ga = wr_[r] * la * rA[r];
        float gb = wr_[r] * lb * rB[r];
        float gc = wr_[r] * lc * rC[r];
        acc[tt] += gb;
        acc[2+tt] = fmaf(sv[(r*2+tt)*3+0], ga, fmaf(sdir[3*r+0], gc, acc[2+tt]));
        acc[4+tt] = fmaf(sv[(r*2+tt)*3+1], ga, fmaf(sdir[3*r+1], gc, acc[4+tt]));
        acc[6+tt] = fmaf(sv[(r*2+tt)*3+2], ga, fmaf(sdir[3*r+2], gc, acc[6+tt]));
      }
    }
    if (pf) issueV(ebNext);   // V consumed -> re-issue for next group
  };

  #pragma unroll
  for (int q = 0; q < 8; ++q) acc[q] = 0.f;

  body(eb0 + 16, true);    // compute eg0, prefetch eg1
  body(0, false);          // compute eg1, no prefetch

  #pragma unroll
  for (int q = 0; q < 8; ++q) {
    acc[q] += __shfl_xor(acc[q], 16);
    acc[q] += __shfl_xor(acc[q], 32);
  }
  if (l < 16) {
    float* os = OUT + (size_t)n * 32;
    os[col16]      = acc[0];
    os[16 + col16] = acc[1];
    float* ov = OUT + (size_t)n_nodes * 32 + (size_t)n * 96;
    ov[     col16] = acc[2]; ov[16 + col16] = acc[3];
    ov[32 + col16] = acc[4]; ov[48 + col16] = acc[5];
    ov[64 + col16] = acc[6]; ov[80 + col16] = acc[7];
  }
}

extern "C" void kernel_launch(void* const* d_in, const int* in_sizes, int n_in,
                              void* d_out, int out_size, void* d_ws, size_t ws_size,
                              hipStream_t stream) {
  const float* S    = (const float*)d_in[0];
  const float* V    = (const float*)d_in[1];
  const float* EXPN = (const float*)d_in[2];
  const float* DIR  = (const float*)d_in[3];
  const float* MASK = (const float*)d_in[4];
  const float* DIST = (const float*)d_in[5];
  const float* W1   = (const float*)d_in[6];
  const float* B1   = (const float*)d_in[7];
  const float* W2   = (const float*)d_in[8];
  const float* B2   = (const float*)d_in[9];
  const float* WR   = (const float*)d_in[10];
  const float* BR   = (const float*)d_in[11];
  float* OUT = (float*)d_out;

  const int n_nodes = in_sizes[0] / 1024;            // 30000
  const int grid = (n_nodes + NPB - 1) / NPB;        // 7500

  hipLaunchKernelGGL(deepdft_v4, dim3(grid), dim3(256), 0, stream,
                     S, V, EXPN, DIR, MASK, DIST, W1, B1, W2, B2, WR, BR,
                     OUT, n_nodes);
}